// Round 1
// baseline (161.542 us; speedup 1.0000x reference)
//
#include <hip/hip_runtime.h>
#include <math.h>

#define NB 8192
#define D 768
#define EPSV 1e-8f
#define BM 128
#define BK 64

typedef float f32x4 __attribute__((ext_vector_type(4)));
typedef short s16x8 __attribute__((ext_vector_type(8)));

// ---------- helpers ----------
__device__ __forceinline__ unsigned short f2bf(float f) {
  // round-to-nearest-even float -> bf16 bits
  unsigned u = __float_as_uint(f);
  u += 0x7fffu + ((u >> 16) & 1u);
  return (unsigned short)(u >> 16);
}

// order-preserving float -> uint mapping (for atomicMax on signed floats)
__device__ __forceinline__ unsigned encf(float f) {
  unsigned u = __float_as_uint(f);
  return (u & 0x80000000u) ? ~u : (u | 0x80000000u);
}
__device__ __forceinline__ float decf(unsigned u) {
  return (u & 0x80000000u) ? __uint_as_float(u & 0x7fffffffu)
                           : __uint_as_float(~u);
}

__device__ __forceinline__ void mfma_bf16(f32x4& c, s16x8 a, s16x8 b) {
  asm("v_mfma_f32_16x16x32_bf16 %0, %1, %2, %0" : "+v"(c) : "v"(a), "v"(b));
}

// ---------- kernel 1: L2-normalize rows, write bf16 ----------
__global__ __launch_bounds__(256) void normalize_kernel(
    const float* __restrict__ in, unsigned short* __restrict__ xb) {
  const int row = blockIdx.x;
  const int t = threadIdx.x;
  float4 v = make_float4(0.f, 0.f, 0.f, 0.f);
  const float4* rp = (const float4*)(in + (size_t)row * D);
  if (t < D / 4) v = rp[t];
  float ss = v.x * v.x + v.y * v.y + v.z * v.z + v.w * v.w;
#pragma unroll
  for (int m = 1; m < 64; m <<= 1) ss += __shfl_xor(ss, m, 64);
  __shared__ float wss[4];
  if ((t & 63) == 0) wss[t >> 6] = ss;
  __syncthreads();
  float tot = wss[0] + wss[1] + wss[2] + wss[3];
  float inv = 1.0f / fmaxf(sqrtf(tot), EPSV);
  if (t < D / 4) {
    ushort4 o;
    o.x = f2bf(v.x * inv);
    o.y = f2bf(v.y * inv);
    o.z = f2bf(v.z * inv);
    o.w = f2bf(v.w * inv);
    *(ushort4*)(xb + (size_t)row * D + t * 4) = o;
  }
}

// ---------- kernel 2: Gram-matrix tiles + fused per-row max ----------
// C tile = X[brow*128 .. +128) . X[bcol*128 .. +128)^T ; per-row max -> atomicMax
__global__ __launch_bounds__(256) void gemm_max_kernel(
    const unsigned short* __restrict__ xb, unsigned* __restrict__ gmax) {
  __shared__ unsigned short As[BM][BK];
  __shared__ unsigned short Bs[BM][BK];
  const int t = threadIdx.x;
  const int w = t >> 6;   // wave 0..3
  const int l = t & 63;   // lane
  const int brow = blockIdx.y, bcol = blockIdx.x;
  const int wm = w >> 1, wn = w & 1;  // 2x2 wave grid of 64x64 quadrants

  f32x4 acc[4][4] = {};

  const int lrow = l >> 3;        // 0..7  (8 lanes per 128B row)
  const int lcol = (l & 7) * 8;   // element col within BK

#pragma unroll 1
  for (int kt = 0; kt < D / BK; ++kt) {
    const int k0 = kt * BK;
    __syncthreads();  // previous compute done before overwriting LDS
    // stage A and B tiles: per wave 4 issues x 8 rows each
#pragma unroll
    for (int it = 0; it < 4; ++it) {
      const int rbase = it * 32 + w * 8;
      const int r = rbase + lrow;
      const unsigned short* ga = xb + (size_t)(brow * BM + r) * D + k0 + lcol;
      __builtin_amdgcn_global_load_lds(
          (const __attribute__((address_space(1))) void*)ga,
          (__attribute__((address_space(3))) void*)&As[rbase][0], 16, 0, 0);
      const unsigned short* gb = xb + (size_t)(bcol * BM + r) * D + k0 + lcol;
      __builtin_amdgcn_global_load_lds(
          (const __attribute__((address_space(1))) void*)gb,
          (__attribute__((address_space(3))) void*)&Bs[rbase][0], 16, 0, 0);
    }
    __syncthreads();  // drains vmcnt(0): tiles resident

#pragma unroll
    for (int kk = 0; kk < 2; ++kk) {
      const int kc = kk * 32 + (l >> 4) * 8;
      s16x8 af[4], bf_[4];
#pragma unroll
      for (int i = 0; i < 4; ++i) {
        af[i] = *(const s16x8*)&As[wm * 64 + i * 16 + (l & 15)][kc];
        bf_[i] = *(const s16x8*)&Bs[wn * 64 + i * 16 + (l & 15)][kc];
      }
#pragma unroll
      for (int i = 0; i < 4; ++i)
#pragma unroll
        for (int j = 0; j < 4; ++j) mfma_bf16(acc[i][j], af[i], bf_[j]);
    }
  }

  // epilogue: per-row max across this tile's 128 cols, then global atomicMax.
  // C/D layout (16x16x32): col = lane&15, row = (lane>>4)*4 + reg  [m89/m91]
  const int q = l >> 4;
  const int c0 = l & 15;
#pragma unroll
  for (int am = 0; am < 4; ++am) {
#pragma unroll
    for (int reg = 0; reg < 4; ++reg) {
      const int grow = brow * BM + wm * 64 + am * 16 + q * 4 + reg;
      float v = -INFINITY;
#pragma unroll
      for (int an = 0; an < 4; ++an) {
        const int gcol = bcol * BM + wn * 64 + an * 16 + c0;
        float val = acc[am][an][reg];
        if (grow == gcol) val = -1.0f;  // mask self
        v = fmaxf(v, val);
      }
      // reduce across the 16 lanes of this quarter-group (cols)
      v = fmaxf(v, __shfl_xor(v, 1));
      v = fmaxf(v, __shfl_xor(v, 2));
      v = fmaxf(v, __shfl_xor(v, 4));
      v = fmaxf(v, __shfl_xor(v, 8));
      if (c0 == 0) atomicMax(&gmax[grow], encf(v));
    }
  }
}

// ---------- kernel 3: loss = -mean(log(dist + eps)) ----------
__global__ __launch_bounds__(1024) void loss_kernel(
    const unsigned* __restrict__ gmax, float* __restrict__ out) {
  const int t = threadIdx.x;
  float s = 0.f;
  for (int i = t; i < NB; i += 1024) {
    float dot = decf(gmax[i]);
    float d2 = fmaxf(2.0f - 2.0f * dot, 0.0f);
    s += logf(sqrtf(d2) + EPSV);
  }
#pragma unroll
  for (int m = 1; m < 64; m <<= 1) s += __shfl_xor(s, m, 64);
  __shared__ float wsum[16];
  if ((t & 63) == 0) wsum[t >> 6] = s;
  __syncthreads();
  if (t == 0) {
    float tot = 0.f;
#pragma unroll
    for (int i = 0; i < 16; ++i) tot += wsum[i];
    out[0] = -tot / (float)NB;
  }
}

// ---------- launch ----------
extern "C" void kernel_launch(void* const* d_in, const int* in_sizes, int n_in,
                              void* d_out, int out_size, void* d_ws,
                              size_t ws_size, hipStream_t stream) {
  const float* in = (const float*)d_in[0];
  float* out = (float*)d_out;
  unsigned* gmax = (unsigned*)d_ws;                              // 8192 u32
  unsigned short* xb = (unsigned short*)((char*)d_ws + 32768);   // bf16 x

  hipMemsetAsync(gmax, 0, NB * sizeof(unsigned), stream);  // enc floor
  normalize_kernel<<<NB, 256, 0, stream>>>(in, xb);
  dim3 grid(NB / BM, NB / BM);
  gemm_max_kernel<<<grid, 256, 0, stream>>>(xb, gmax);
  loss_kernel<<<1, 1024, 0, stream>>>(gmax, out);
}

// Round 2
// 104.526 us; speedup vs baseline: 1.5455x; 1.5455x over previous
//
#include <hip/hip_runtime.h>
#include <math.h>

#define NB 8192
#define D 768
#define EPSV 1e-8f
#define BM 128
#define BK 64

typedef float f32x4 __attribute__((ext_vector_type(4)));
typedef short s16x8 __attribute__((ext_vector_type(8)));

// ---------- helpers ----------
__device__ __forceinline__ unsigned short f2bf(float f) {
  unsigned u = __float_as_uint(f);
  u += 0x7fffu + ((u >> 16) & 1u);
  return (unsigned short)(u >> 16);
}

// order-preserving float -> uint mapping (for atomicMax on signed floats)
__device__ __forceinline__ unsigned encf(float f) {
  unsigned u = __float_as_uint(f);
  return (u & 0x80000000u) ? ~u : (u | 0x80000000u);
}
__device__ __forceinline__ float decf(unsigned u) {
  return (u & 0x80000000u) ? __uint_as_float(u & 0x7fffffffu)
                           : __uint_as_float(~u);
}

__device__ __forceinline__ void mfma_bf16(f32x4& c, s16x8 a, s16x8 b) {
  asm("v_mfma_f32_16x16x32_bf16 %0, %1, %2, %0" : "+v"(c) : "v"(a), "v"(b));
}

// ---------- kernel 1: L2-normalize rows, write bf16 ----------
__global__ __launch_bounds__(256) void normalize_kernel(
    const float* __restrict__ in, unsigned short* __restrict__ xb) {
  const int row = blockIdx.x;
  const int t = threadIdx.x;
  float4 v = make_float4(0.f, 0.f, 0.f, 0.f);
  const float4* rp = (const float4*)(in + (size_t)row * D);
  if (t < D / 4) v = rp[t];
  float ss = v.x * v.x + v.y * v.y + v.z * v.z + v.w * v.w;
#pragma unroll
  for (int m = 1; m < 64; m <<= 1) ss += __shfl_xor(ss, m, 64);
  __shared__ float wss[4];
  if ((t & 63) == 0) wss[t >> 6] = ss;
  __syncthreads();
  float tot = wss[0] + wss[1] + wss[2] + wss[3];
  float inv = 1.0f / fmaxf(sqrtf(tot), EPSV);
  if (t < D / 4) {
    ushort4 o;
    o.x = f2bf(v.x * inv);
    o.y = f2bf(v.y * inv);
    o.z = f2bf(v.z * inv);
    o.w = f2bf(v.w * inv);
    *(ushort4*)(xb + (size_t)row * D + t * 4) = o;
  }
}

// ---------- kernel 2: lower-triangle Gram tiles + fused row/col max ----------
// Symmetry: tile (br,bc) with bc<=br; off-diag tiles fold per-row AND per-col
// max into gmax. Diagonal tiles are symmetric -> row max (self-masked) only.
__global__ __launch_bounds__(256) void gemm_max_kernel(
    const unsigned short* __restrict__ xb, unsigned* __restrict__ gmax) {
  __shared__ unsigned short As[BM][BK];
  __shared__ unsigned short Bs[BM][BK];
  const int t = threadIdx.x;
  const int w = t >> 6;   // wave 0..3
  const int l = t & 63;   // lane
  const int wm = w >> 1, wn = w & 1;  // 2x2 wave grid of 64x64 quadrants

  // triangular decode: blockIdx.x -> (brow, bcol), bcol <= brow
  const int idx = blockIdx.x;
  int brow = (int)((sqrtf(8.0f * (float)idx + 1.0f) - 1.0f) * 0.5f);
  while ((brow + 1) * (brow + 2) / 2 <= idx) ++brow;
  while (brow * (brow + 1) / 2 > idx) --brow;
  const int bcol = idx - brow * (brow + 1) / 2;
  const bool diag = (brow == bcol);

  f32x4 acc[4][4] = {};

  const int lrow = l >> 3;        // 0..7  (8 lanes per 128B row)
  const int lcol = (l & 7) * 8;   // element col within BK

#pragma unroll 1
  for (int kt = 0; kt < D / BK; ++kt) {
    const int k0 = kt * BK;
    __syncthreads();  // previous compute done before overwriting LDS
#pragma unroll
    for (int it = 0; it < 4; ++it) {
      const int rbase = it * 32 + w * 8;
      const int r = rbase + lrow;
      const unsigned short* ga = xb + (size_t)(brow * BM + r) * D + k0 + lcol;
      __builtin_amdgcn_global_load_lds(
          (const __attribute__((address_space(1))) void*)ga,
          (__attribute__((address_space(3))) void*)&As[rbase][0], 16, 0, 0);
      const unsigned short* gb = xb + (size_t)(bcol * BM + r) * D + k0 + lcol;
      __builtin_amdgcn_global_load_lds(
          (const __attribute__((address_space(1))) void*)gb,
          (__attribute__((address_space(3))) void*)&Bs[rbase][0], 16, 0, 0);
    }
    __syncthreads();  // drains vmcnt(0): tiles resident

#pragma unroll
    for (int kk = 0; kk < 2; ++kk) {
      const int kc = kk * 32 + (l >> 4) * 8;
      s16x8 af[4], bf_[4];
#pragma unroll
      for (int i = 0; i < 4; ++i) {
        af[i] = *(const s16x8*)&As[wm * 64 + i * 16 + (l & 15)][kc];
        bf_[i] = *(const s16x8*)&Bs[wn * 64 + i * 16 + (l & 15)][kc];
      }
#pragma unroll
      for (int i = 0; i < 4; ++i)
#pragma unroll
        for (int j = 0; j < 4; ++j) mfma_bf16(acc[i][j], af[i], bf_[j]);
    }
  }

  // epilogue. C/D layout (16x16x32): col = lane&15, row = (lane>>4)*4 + reg
  const int q = l >> 4;
  const int c0 = l & 15;

  // per-row max over this tile's 128 cols -> gmax[row]
#pragma unroll
  for (int am = 0; am < 4; ++am) {
#pragma unroll
    for (int reg = 0; reg < 4; ++reg) {
      const int grow = brow * BM + wm * 64 + am * 16 + q * 4 + reg;
      float v = -INFINITY;
#pragma unroll
      for (int an = 0; an < 4; ++an) {
        float val = acc[am][an][reg];
        if (diag && grow == bcol * BM + wn * 64 + an * 16 + c0) val = -1.0f;
        v = fmaxf(v, val);
      }
      v = fmaxf(v, __shfl_xor(v, 1));
      v = fmaxf(v, __shfl_xor(v, 2));
      v = fmaxf(v, __shfl_xor(v, 4));
      v = fmaxf(v, __shfl_xor(v, 8));
      if (c0 == 0) atomicMax(&gmax[grow], encf(v));
    }
  }

  // per-col max over this tile's 128 rows -> gmax[col]  (off-diagonal only)
  if (!diag) {
#pragma unroll
    for (int an = 0; an < 4; ++an) {
      float v = -INFINITY;
#pragma unroll
      for (int am = 0; am < 4; ++am)
#pragma unroll
        for (int reg = 0; reg < 4; ++reg) v = fmaxf(v, acc[am][an][reg]);
      v = fmaxf(v, __shfl_xor(v, 16));
      v = fmaxf(v, __shfl_xor(v, 32));
      if (q == 0) {
        const int gcol = bcol * BM + wn * 64 + an * 16 + c0;
        atomicMax(&gmax[gcol], encf(v));
      }
    }
  }
}

// ---------- kernel 3: loss = -mean(log(dist + eps)) ----------
__global__ __launch_bounds__(1024) void loss_kernel(
    const unsigned* __restrict__ gmax, float* __restrict__ out) {
  const int t = threadIdx.x;
  float s = 0.f;
  for (int i = t; i < NB; i += 1024) {
    float dot = decf(gmax[i]);
    float d2 = fmaxf(2.0f - 2.0f * dot, 0.0f);
    s += logf(sqrtf(d2) + EPSV);
  }
#pragma unroll
  for (int m = 1; m < 64; m <<= 1) s += __shfl_xor(s, m, 64);
  __shared__ float wsum[16];
  if ((t & 63) == 0) wsum[t >> 6] = s;
  __syncthreads();
  if (t == 0) {
    float tot = 0.f;
#pragma unroll
    for (int i = 0; i < 16; ++i) tot += wsum[i];
    out[0] = -tot / (float)NB;
  }
}

// ---------- launch ----------
extern "C" void kernel_launch(void* const* d_in, const int* in_sizes, int n_in,
                              void* d_out, int out_size, void* d_ws,
                              size_t ws_size, hipStream_t stream) {
  const float* in = (const float*)d_in[0];
  float* out = (float*)d_out;
  unsigned* gmax = (unsigned*)d_ws;                              // 8192 u32
  unsigned short* xb = (unsigned short*)((char*)d_ws + 32768);   // bf16 x

  hipMemsetAsync(gmax, 0, NB * sizeof(unsigned), stream);
  normalize_kernel<<<NB, 256, 0, stream>>>(in, xb);
  const int nblk = (NB / BM) * (NB / BM + 1) / 2;  // 2080 lower-tri tiles
  gemm_max_kernel<<<nblk, 256, 0, stream>>>(xb, gmax);
  loss_kernel<<<1, 1024, 0, stream>>>(gmax, out);
}